// Round 1
// baseline (8197.263 us; speedup 1.0000x reference)
//
#include <hip/hip_runtime.h>
#include <math.h>

#define Nn 19
#define Dd 64
#define KE 16
#define DIN 80      // Dd + KE
#define Tt 1024
#define Bb 16
#define Gg (Bb*Tt)
#define ALPHAc 0.05f
#define HOPW 0.475f  // (1-alpha)/K, K=2
#define LNEPS 1e-5f

__device__ __forceinline__ float softplusf(float x){
  return (x > 0.f) ? (x + log1pf(expf(-x))) : log1pf(expf(x));
}

__device__ __forceinline__ float wsum(float v){
  #pragma unroll
  for (int o = 32; o > 0; o >>= 1) v += __shfl_xor(v, o, 64);
  return v;
}

__global__ __launch_bounds__(64)
void gcm_kernel(
  const float* __restrict__ feat,
  const float* __restrict__ adj,
  const float* __restrict__ ew_p, const float* __restrict__ eb_p,
  const float* __restrict__ W0, const float* __restrict__ b0,
  const float* __restrict__ W1, const float* __restrict__ b1,
  const float* __restrict__ g0, const float* __restrict__ be0,
  const float* __restrict__ g1, const float* __restrict__ be1,
  float* __restrict__ out)
{
  const int g    = blockIdx.x;
  const int lane = threadIdx.x;
  const int b    = g >> 10;        // T = 1024
  const int t    = g & (Tt - 1);

  __shared__ float  anS[Nn*Nn];    // gcn-normalized adjacency
  __shared__ float  peS[Nn*KE];    // positional encodings
  __shared__ double evS[Nn];       // eigenvalues
  __shared__ float  rsS[Nn];       // rsqrt row sums (PE norm)
  __shared__ float  csS[Nn];       // rsqrt col sums (gcn norm)
  __shared__ __align__(16) char arena[6080];
  double* Ad   = (double*)(arena);          // [19][20] fp64 Jacobi work matrix
  float*  Vf   = (float*)(arena + 3040);    // [19][20] eigenvectors
  float*  adjS = (float*)(arena + 4560);    // [361] raw adjacency
  float*  hb   = (float*)(arena);           // phase2: [19][80] then [19][64]

  // ---- issue feature loads early (held in VGPRs through the eig phase) ----
  float xr[Nn];
  const float* fb = feat + (((size_t)b*Nn)*Tt + t)*Dd + lane;
  #pragma unroll
  for (int n = 0; n < Nn; ++n) xr[n] = fb[(size_t)n*Tt*Dd];

  const float ew = ew_p[0], eb = eb_p[0];

  for (int idx = lane; idx < Nn*Nn; idx += 64)
    adjS[idx] = adj[(size_t)g*(Nn*Nn) + idx];
  __syncthreads();

  // row sums of raw adjacency (PE normalization)
  if (lane < Nn) {
    float rs = 0.f;
    for (int j = 0; j < Nn; ++j) rs += adjS[lane*Nn + j];
    rsS[lane] = rsqrtf(fmaxf(rs, 1e-6f));
  }
  // edge-transformed weights w into anS
  for (int idx = lane; idx < Nn*Nn; idx += 64) {
    int i = idx / Nn, j = idx - i*Nn;
    float a = adjS[idx];
    bool m = a > 0.f;
    float wv = m ? softplusf(a*ew + eb) : ((i == j) ? 1.f : 0.f);
    anS[idx] = wv;
  }
  __syncthreads();
  // column sums -> dis
  if (lane < Nn) {
    float cs = 0.f;
    for (int i = 0; i < Nn; ++i) cs += anS[i*Nn + lane];
    csS[lane] = (cs > 0.f) ? rsqrtf(fmaxf(cs, 1e-30f)) : 0.f;
  }
  __syncthreads();
  // normalize anS; build symmetric Laplacian (fp64) and V = I
  for (int idx = lane; idx < Nn*Nn; idx += 64) {
    int i = idx / Nn, j = idx - i*Nn;
    anS[idx] = csS[i]*anS[idx]*csS[j];
    float anij = rsS[i]*adjS[i*Nn + j]*rsS[j];
    float anji = rsS[j]*adjS[j*Nn + i]*rsS[i];
    double m = ((i == j) ? (1.0 + 1e-5) : 0.0) - 0.5*((double)anij + (double)anji);
    Ad[i*20 + j] = m;
    Vf[i*20 + j] = (i == j) ? 1.f : 0.f;
  }
  __syncthreads();

  // ---- cyclic Jacobi eigensolver (A fp64, V fp32) ----
  for (int sweep = 0; sweep < 30; ++sweep) {
    double off = 0.0;
    for (int idx = lane; idx < Nn*Nn; idx += 64) {
      int i = idx / Nn, j = idx - i*Nn;
      if (i < j) { double v = Ad[i*20 + j]; off += v*v; }
    }
    #pragma unroll
    for (int o = 32; o > 0; o >>= 1) off += __shfl_xor(off, o, 64);
    if (off < 1e-22) break;
    for (int p = 0; p < Nn - 1; ++p) {
      for (int q = p + 1; q < Nn; ++q) {
        double apq = Ad[p*20 + q];                 // broadcast read (uniform)
        if (fabs(apq) > 1e-15) {
          double app = Ad[p*20 + p], aqq = Ad[q*20 + q];
          double tau = (aqq - app) / (2.0*apq);
          double tt  = sqrt(1.0 + tau*tau);
          double tv  = (tau >= 0.0) ? 1.0/(tau + tt) : 1.0/(tau - tt);
          double c   = 1.0/sqrt(1.0 + tv*tv);
          double s   = tv*c;
          double akp = 0.0, akq = 0.0; float vkp = 0.f, vkq = 0.f;
          if (lane < Nn) {
            akp = Ad[lane*20 + p]; akq = Ad[lane*20 + q];
            vkp = Vf[lane*20 + p]; vkq = Vf[lane*20 + q];
          }
          __syncthreads();
          if (lane < Nn) {
            double nkp = c*akp - s*akq;
            double nkq = s*akp + c*akq;
            if (lane == p) {
              nkp = c*c*app - 2.0*c*s*apq + s*s*aqq;
              nkq = 0.0;
            } else if (lane == q) {
              nkp = 0.0;
              nkq = s*s*app + 2.0*c*s*apq + c*c*aqq;
            }
            Ad[lane*20 + p] = nkp; Ad[p*20 + lane] = nkp;
            Ad[lane*20 + q] = nkq; Ad[q*20 + lane] = nkq;
            float fc = (float)c, fs = (float)s;
            Vf[lane*20 + p] = fc*vkp - fs*vkq;
            Vf[lane*20 + q] = fs*vkp + fc*vkq;
          }
          __syncthreads();
        }
      }
    }
  }

  // ---- eigenvalue ranks; write 16 smallest eigenvectors (sign-fixed) ----
  if (lane < Nn) evS[lane] = Ad[lane*20 + lane];
  __syncthreads();
  if (lane < Nn) {
    double lam = evS[lane];
    int r = 0;
    for (int j = 0; j < Nn; ++j) {
      double lj = evS[j];
      r += (lj < lam) || (lj == lam && j < lane);
    }
    if (r < KE) {
      float sacc = 0.f;
      for (int n = 0; n < Nn; ++n) sacc += Vf[n*20 + lane];
      float sgn = (sacc < 0.f) ? -1.f : 1.f;
      for (int n = 0; n < Nn; ++n) peS[n*KE + r] = Vf[n*20 + lane]*sgn;
    }
  }
  __syncthreads();   // peS done; arena (Ad/Vf/adjS) now reusable as hb

  // ---- SSGConv layer 0: h = a*x + 0.475*(P x + P^2 x), P = anorm^T ----
  // pass 0: feature columns d = lane (in registers)
  {
    float x1[Nn], x2[Nn];
    for (int j = 0; j < Nn; ++j) {
      float acc = 0.f;
      #pragma unroll
      for (int i = 0; i < Nn; ++i) acc += anS[i*Nn + j]*xr[i];
      x1[j] = acc;
    }
    for (int j = 0; j < Nn; ++j) {
      float acc = 0.f;
      #pragma unroll
      for (int i = 0; i < Nn; ++i) acc += anS[i*Nn + j]*x1[i];
      x2[j] = acc;
    }
    #pragma unroll
    for (int n = 0; n < Nn; ++n)
      hb[n*DIN + lane] = ALPHAc*xr[n] + HOPW*(x1[n] + x2[n]);
  }
  // pass 1: PE columns d = 64 + lane (lanes 0..15)
  if (lane < KE) {
    float xc[Nn], x1[Nn], x2[Nn];
    #pragma unroll
    for (int n = 0; n < Nn; ++n) xc[n] = peS[n*KE + lane];
    for (int j = 0; j < Nn; ++j) {
      float acc = 0.f;
      #pragma unroll
      for (int i = 0; i < Nn; ++i) acc += anS[i*Nn + j]*xc[i];
      x1[j] = acc;
    }
    for (int j = 0; j < Nn; ++j) {
      float acc = 0.f;
      #pragma unroll
      for (int i = 0; i < Nn; ++i) acc += anS[i*Nn + j]*x1[i];
      x2[j] = acc;
    }
    #pragma unroll
    for (int n = 0; n < Nn; ++n)
      hb[n*DIN + Dd + lane] = ALPHAc*xc[n] + HOPW*(x1[n] + x2[n]);
  }
  __syncthreads();

  // ---- matmul0: out0[n][o=lane] = sum_k hb[n][k] * W0[o][k] + b0[o]; LN0 ----
  float acc[Nn];
  #pragma unroll
  for (int n = 0; n < Nn; ++n) acc[n] = 0.f;
  {
    const float* w0r = W0 + lane*DIN;
    #pragma unroll 8
    for (int k = 0; k < DIN; ++k) {
      float wv = w0r[k];
      #pragma unroll
      for (int n = 0; n < Nn; ++n) acc[n] += hb[n*DIN + k]*wv;
    }
  }
  float yv[Nn];
  {
    float bias = b0[lane], gam = g0[lane], bet = be0[lane];
    #pragma unroll
    for (int n = 0; n < Nn; ++n) {
      float v  = acc[n] + bias;
      float mu = wsum(v)*(1.f/64.f);
      float d  = v - mu;
      float var = wsum(d*d)*(1.f/64.f);
      yv[n] = d*rsqrtf(var + LNEPS)*gam + bet;
    }
  }

  // ---- SSGConv layer 1 (in registers), reuse hb as [19][64] ----
  {
    float x1[Nn], x2[Nn];
    for (int j = 0; j < Nn; ++j) {
      float a2 = 0.f;
      #pragma unroll
      for (int i = 0; i < Nn; ++i) a2 += anS[i*Nn + j]*yv[i];
      x1[j] = a2;
    }
    for (int j = 0; j < Nn; ++j) {
      float a2 = 0.f;
      #pragma unroll
      for (int i = 0; i < Nn; ++i) a2 += anS[i*Nn + j]*x1[i];
      x2[j] = a2;
    }
    __syncthreads();
    #pragma unroll
    for (int n = 0; n < Nn; ++n)
      hb[n*Dd + lane] = ALPHAc*yv[n] + HOPW*(x1[n] + x2[n]);
    __syncthreads();
  }

  // ---- matmul1 + residual + LN1 + store ----
  float acc1[Nn];
  #pragma unroll
  for (int n = 0; n < Nn; ++n) acc1[n] = 0.f;
  {
    const float* w1r = W1 + lane*Dd;
    #pragma unroll 8
    for (int k = 0; k < Dd; ++k) {
      float wv = w1r[k];
      #pragma unroll
      for (int n = 0; n < Nn; ++n) acc1[n] += hb[n*Dd + k]*wv;
    }
  }
  {
    float bias = b1[lane], gam = g1[lane], bet = be1[lane];
    float* ob = out + (((size_t)b*Nn)*Tt + t)*Dd + lane;
    #pragma unroll
    for (int n = 0; n < Nn; ++n) {
      float v  = acc1[n] + bias + yv[n];
      float mu = wsum(v)*(1.f/64.f);
      float d  = v - mu;
      float var = wsum(d*d)*(1.f/64.f);
      ob[(size_t)n*Tt*Dd] = d*rsqrtf(var + LNEPS)*gam + bet;
    }
  }
}

extern "C" void kernel_launch(void* const* d_in, const int* in_sizes, int n_in,
                              void* d_out, int out_size, void* d_ws, size_t ws_size,
                              hipStream_t stream) {
  (void)in_sizes; (void)n_in; (void)out_size; (void)d_ws; (void)ws_size;
  const float* feat = (const float*)d_in[0];
  const float* adj  = (const float*)d_in[1];
  const float* ew   = (const float*)d_in[2];
  const float* eb   = (const float*)d_in[3];
  const float* W0   = (const float*)d_in[4];
  const float* b0   = (const float*)d_in[5];
  const float* W1   = (const float*)d_in[6];
  const float* b1   = (const float*)d_in[7];
  const float* g0   = (const float*)d_in[8];
  const float* be0  = (const float*)d_in[9];
  const float* g1   = (const float*)d_in[10];
  const float* be1  = (const float*)d_in[11];
  float* out = (float*)d_out;

  hipLaunchKernelGGL(gcm_kernel, dim3(Gg), dim3(64), 0, stream,
                     feat, adj, ew, eb, W0, b0, W1, b1, g0, be0, g1, be1, out);
}

// Round 2
// 1609.164 us; speedup vs baseline: 5.0941x; 5.0941x over previous
//
#include <hip/hip_runtime.h>
#include <math.h>

#define Nn 19
#define Dd 64
#define KE 16
#define DIN 80
#define Tt 1024
#define Bb 16
#define Gg (Bb*Tt)
#define ALPHAc 0.05f
#define HOPW 0.475f
#define LNEPS 1e-5f

#define AN_STRIDE 368            // floats per graph for a_norm in ws (361 used)
#define PE_STRIDE 304            // floats per graph for pe in ws (19*16)
#define WS_NEED ((size_t)Gg * (AN_STRIDE + PE_STRIDE) * 4)

__device__ __forceinline__ float softplusf(float x){
  return (x > 0.f) ? (x + log1pf(expf(-x))) : log1pf(expf(x));
}

__device__ __forceinline__ float wsum(float v){
  #pragma unroll
  for (int o = 32; o > 0; o >>= 1) v += __shfl_xor(v, o, 64);
  return v;
}

// intra-wave LDS ordering fence: LDS ops from one wave execute in order;
// this only stops the compiler from reordering across it. Zero instructions.
__device__ __forceinline__ void wsync(){
  __asm__ volatile("" ::: "memory");
  __builtin_amdgcn_wave_barrier();
  __asm__ volatile("" ::: "memory");
}

// ======================= kernel 1: gcn_norm + eigensolver =======================
// 4 waves/block, one graph per wave, per-wave LDS arena, no block barriers.
#define ARENA_BYTES 6528
__global__ __launch_bounds__(256)
void eig_kernel(const float* __restrict__ adj,
                const float* __restrict__ ew_p, const float* __restrict__ eb_p,
                float* __restrict__ anW, float* __restrict__ peW)
{
  const int wid  = threadIdx.x >> 6;
  const int lane = threadIdx.x & 63;
  const int g    = blockIdx.x * 4 + wid;

  __shared__ __align__(16) char arenaAll[4 * ARENA_BYTES];
  char* arena = arenaAll + wid * ARENA_BYTES;
  double* Ad  = (double*)(arena);            // [20][20] fp64 work matrix (3200 B)
  float*  Vf  = (float*) (arena + 3200);     // [20][20] eigenvectors (1600 B)
  float*  adjS= (float*) (arena + 3200);     // [361] raw adj (overlaps Vf; dead before Vf init)
  float*  peB = (float*) (arena + 4800);     // [304] pe staging (1216 B)
  float*  wS  = (float*) (arena + 4800);     // [361] softplus weights (overlaps peB; dead first)
  float*  rsS = (float*) (arena + 6256);     // [19]
  float*  csS = (float*) (arena + 6336);     // [19]
  float*  cS  = (float*) (arena + 6416);     // [10]
  float*  sS  = (float*) (arena + 6456);     // [10]

  const float ew = ew_p[0], eb = eb_p[0];

  for (int idx = lane; idx < Nn*Nn; idx += 64)
    adjS[idx] = adj[(size_t)g*(Nn*Nn) + idx];
  wsync();

  // softplus edge weights (+ missing self loops)
  for (int idx = lane; idx < Nn*Nn; idx += 64) {
    int i = idx / Nn, j = idx - i*Nn;
    float a = adjS[idx];
    wS[idx] = (a > 0.f) ? softplusf(a*ew + eb) : ((i == j) ? 1.f : 0.f);
  }
  // PE row sums from raw adj
  if (lane < Nn) {
    float rs = 0.f;
    for (int j = 0; j < Nn; ++j) rs += adjS[lane*Nn + j];
    rsS[lane] = rsqrtf(fmaxf(rs, 1e-6f));
  }
  wsync();
  // gcn col sums
  if (lane < Nn) {
    float cs = 0.f;
    for (int i = 0; i < Nn; ++i) cs += wS[i*Nn + lane];
    csS[lane] = (cs > 0.f) ? rsqrtf(fmaxf(cs, 1e-30f)) : 0.f;
  }
  wsync();
  // write normalized adjacency straight to ws
  for (int idx = lane; idx < Nn*Nn; idx += 64) {
    int i = idx / Nn, j = idx - i*Nn;
    anW[(size_t)g*AN_STRIDE + idx] = csS[i]*wS[idx]*csS[j];
  }
  // build symmetrized Laplacian (fp64), padded to 20 with dummy eigval 1e6
  for (int idx = lane; idx < Nn*Nn; idx += 64) {
    int i = idx / Nn, j = idx - i*Nn;
    float anij = rsS[i]*adjS[i*Nn + j]*rsS[j];
    float anji = rsS[j]*adjS[j*Nn + i]*rsS[i];
    Ad[i*20 + j] = ((i == j) ? (1.0 + 1e-5) : 0.0) - 0.5*((double)anij + (double)anji);
  }
  if (lane < 20) {
    Ad[lane*20 + 19] = 0.0;
    Ad[19*20 + lane] = (lane == 19) ? 1e6 : 0.0;
  }
  wsync();
  // V = I (kills adjS)
  for (int idx = lane; idx < 400; idx += 64) {
    int i = idx / 20;
    Vf[idx] = (idx == i*21) ? 1.f : 0.f;
  }
  wsync();

  // ---- parallel-pair cyclic Jacobi: 10 disjoint rotations per round ----
  for (int sweep = 0; sweep < 14; ++sweep) {
    float off = 0.f;
    for (int idx = lane; idx < Nn*Nn; idx += 64) {
      int i = idx / Nn, j = idx - i*Nn;
      if (i < j) { float v = (float)Ad[i*20 + j]; off += v*v; }
    }
    #pragma unroll
    for (int o = 32; o > 0; o >>= 1) off += __shfl_xor(off, o, 64);
    if (off < 1e-10f) break;

    for (int r = 0; r < 19; ++r) {
      bool active = false;
      if (lane < 10) {
        int a, b;
        if (lane == 0) { a = r; b = 19; }
        else { a = r + lane; if (a >= 19) a -= 19; b = r + 19 - lane; if (b >= 19) b -= 19; }
        int p = min(a, b), q = max(a, b);
        float apq = (float)Ad[p*20 + q];
        float c = 1.f, s = 0.f;
        if (fabsf(apq) > 1e-12f) {
          float app = (float)Ad[p*20 + p], aqq = (float)Ad[q*20 + q];
          float tau = (aqq - app) / (2.f*apq);
          float tt  = sqrtf(1.f + tau*tau);
          float tv  = (tau >= 0.f) ? 1.f/(tau + tt) : 1.f/(tau - tt);
          c = rsqrtf(1.f + tv*tv);
          s = tv*c;
          active = true;
        }
        cS[lane] = c; sS[lane] = s;
      }
      int anyact = __any(active);
      wsync();
      if (!anyact) continue;

      // phase A: A <- A*J (column update), V <- V*J. 200 items (k,i).
      #pragma unroll
      for (int it = 0; it < 4; ++it) {
        int item = lane + it*64;
        if (item < 200) {
          int k = item / 10, i = item - (item/10)*10;
          int a, b;
          if (i == 0) { a = r; b = 19; }
          else { a = r + i; if (a >= 19) a -= 19; b = r + 19 - i; if (b >= 19) b -= 19; }
          int p = min(a, b), q = max(a, b);
          float c = cS[i], s = sS[i];
          double cd = (double)c, sd = (double)s;
          double akp = Ad[k*20 + p], akq = Ad[k*20 + q];
          Ad[k*20 + p] = cd*akp - sd*akq;
          Ad[k*20 + q] = sd*akp + cd*akq;
          float vkp = Vf[k*20 + p], vkq = Vf[k*20 + q];
          Vf[k*20 + p] = c*vkp - s*vkq;
          Vf[k*20 + q] = s*vkp + c*vkq;
        }
      }
      wsync();
      // phase B: A <- J^T*A (row update)
      #pragma unroll
      for (int it = 0; it < 4; ++it) {
        int item = lane + it*64;
        if (item < 200) {
          int k = item / 10, i = item - (item/10)*10;
          int a, b;
          if (i == 0) { a = r; b = 19; }
          else { a = r + i; if (a >= 19) a -= 19; b = r + 19 - i; if (b >= 19) b -= 19; }
          int p = min(a, b), q = max(a, b);
          float c = cS[i], s = sS[i];
          double cd = (double)c, sd = (double)s;
          double arp = Ad[p*20 + k], arq = Ad[q*20 + k];
          Ad[p*20 + k] = cd*arp - sd*arq;
          Ad[q*20 + k] = sd*arp + cd*arq;
        }
      }
      wsync();
    }
  }

  // ---- rank eigenvalues, sign-fix, stage pe, write out ----
  if (lane < Nn) {
    double lam = Ad[lane*21];
    int rk = 0;
    for (int j = 0; j < Nn; ++j) {
      double lj = Ad[j*21];
      rk += (lj < lam) || (lj == lam && j < lane);
    }
    if (rk < KE) {
      float sacc = 0.f;
      for (int n = 0; n < Nn; ++n) sacc += Vf[n*20 + lane];
      float sgn = (sacc < 0.f) ? -1.f : 1.f;
      for (int n = 0; n < Nn; ++n) peB[n*KE + rk] = Vf[n*20 + lane]*sgn;
    }
  }
  wsync();
  for (int idx = lane; idx < Nn*KE; idx += 64)
    peW[(size_t)g*PE_STRIDE + idx] = peB[idx];
}

// ======================= kernel 2: SSGConv x2 + LN =======================
__global__ __launch_bounds__(64)
void gnn_kernel(const float* __restrict__ feat,
                const float* __restrict__ anW, const float* __restrict__ peW,
                const float* __restrict__ W0, const float* __restrict__ b0,
                const float* __restrict__ W1, const float* __restrict__ b1,
                const float* __restrict__ g0, const float* __restrict__ be0,
                const float* __restrict__ g1, const float* __restrict__ be1,
                float* __restrict__ out)
{
  const int g = blockIdx.x, lane = threadIdx.x;
  const int b = g >> 10, t = g & (Tt - 1);

  __shared__ __align__(16) float anT[400];      // transposed a_norm, rows of 20
  __shared__ __align__(16) float peS[Nn*KE];
  __shared__ __align__(16) float hb[Nn*DIN];

  for (int idx = lane; idx < Nn*Nn; idx += 64) {
    int i = idx / Nn, j = idx - i*Nn;
    anT[j*20 + i] = anW[(size_t)g*AN_STRIDE + idx];
  }
  for (int idx = lane; idx < Nn*KE; idx += 64)
    peS[idx] = peW[(size_t)g*PE_STRIDE + idx];
  if (lane < Nn) anT[lane*20 + 19] = 0.f;

  float xa[Nn];
  const float* fb = feat + (((size_t)b*Nn)*Tt + t)*Dd + lane;
  #pragma unroll
  for (int n = 0; n < Nn; ++n) xa[n] = fb[(size_t)n*Tt*Dd];
  wsync();
  float xb[Nn];
  #pragma unroll
  for (int n = 0; n < Nn; ++n) xb[n] = (lane < KE) ? peS[n*KE + lane] : 0.f;

  // ---- layer0: hop1 for cols {lane, 64+lane} ----
  float x1a[Nn], x1b[Nn];
  #pragma unroll
  for (int j = 0; j < Nn; ++j) {
    float aa = 0.f, ab = 0.f;
    #pragma unroll
    for (int tq = 0; tq < 4; ++tq) {
      float4 a4 = *(const float4*)&anT[j*20 + 4*tq];
      aa += a4.x*xa[4*tq] + a4.y*xa[4*tq+1] + a4.z*xa[4*tq+2] + a4.w*xa[4*tq+3];
      ab += a4.x*xb[4*tq] + a4.y*xb[4*tq+1] + a4.z*xb[4*tq+2] + a4.w*xb[4*tq+3];
    }
    float4 a4 = *(const float4*)&anT[j*20 + 16];
    aa += a4.x*xa[16] + a4.y*xa[17] + a4.z*xa[18];
    ab += a4.x*xb[16] + a4.y*xb[17] + a4.z*xb[18];
    x1a[j] = aa; x1b[j] = ab;
  }
  #pragma unroll
  for (int n = 0; n < Nn; ++n) {
    hb[n*DIN + lane] = ALPHAc*xa[n] + HOPW*x1a[n];
    if (lane < KE) hb[n*DIN + Dd + lane] = ALPHAc*xb[n] + HOPW*x1b[n];
  }
  wsync();
  // hop2 accumulated into hb
  #pragma unroll
  for (int j = 0; j < Nn; ++j) {
    float aa = 0.f, ab = 0.f;
    #pragma unroll
    for (int tq = 0; tq < 4; ++tq) {
      float4 a4 = *(const float4*)&anT[j*20 + 4*tq];
      aa += a4.x*x1a[4*tq] + a4.y*x1a[4*tq+1] + a4.z*x1a[4*tq+2] + a4.w*x1a[4*tq+3];
      ab += a4.x*x1b[4*tq] + a4.y*x1b[4*tq+1] + a4.z*x1b[4*tq+2] + a4.w*x1b[4*tq+3];
    }
    float4 a4 = *(const float4*)&anT[j*20 + 16];
    aa += a4.x*x1a[16] + a4.y*x1a[17] + a4.z*x1a[18];
    ab += a4.x*x1b[16] + a4.y*x1b[17] + a4.z*x1b[18];
    hb[j*DIN + lane] += HOPW*aa;
    if (lane < KE) hb[j*DIN + Dd + lane] += HOPW*ab;
  }
  wsync();

  // ---- matmul0 + LN0 ----
  float acc[Nn];
  #pragma unroll
  for (int n = 0; n < Nn; ++n) acc[n] = 0.f;
  {
    const float4* w0r = (const float4*)(W0 + lane*DIN);
    #pragma unroll
    for (int tq = 0; tq < DIN/4; ++tq) {
      float4 w4 = w0r[tq];
      #pragma unroll
      for (int n = 0; n < Nn; ++n) {
        float4 h4 = *(const float4*)&hb[n*DIN + 4*tq];
        acc[n] += h4.x*w4.x + h4.y*w4.y + h4.z*w4.z + h4.w*w4.w;
      }
    }
  }
  float yv[Nn];
  {
    float bias = b0[lane], gam = g0[lane], bet = be0[lane];
    #pragma unroll
    for (int n = 0; n < Nn; ++n) {
      float v  = acc[n] + bias;
      float mu = wsum(v)*(1.f/64.f);
      float d  = v - mu;
      float var = wsum(d*d)*(1.f/64.f);
      yv[n] = d*rsqrtf(var + LNEPS)*gam + bet;
    }
  }
  wsync();

  // ---- layer1 hops (cols = lane only), hb reused with stride 64 ----
  float x1[Nn];
  #pragma unroll
  for (int j = 0; j < Nn; ++j) {
    float aa = 0.f;
    #pragma unroll
    for (int tq = 0; tq < 4; ++tq) {
      float4 a4 = *(const float4*)&anT[j*20 + 4*tq];
      aa += a4.x*yv[4*tq] + a4.y*yv[4*tq+1] + a4.z*yv[4*tq+2] + a4.w*yv[4*tq+3];
    }
    float4 a4 = *(const float4*)&anT[j*20 + 16];
    aa += a4.x*yv[16] + a4.y*yv[17] + a4.z*yv[18];
    x1[j] = aa;
  }
  #pragma unroll
  for (int n = 0; n < Nn; ++n)
    hb[n*Dd + lane] = ALPHAc*yv[n] + HOPW*x1[n];
  wsync();
  #pragma unroll
  for (int j = 0; j < Nn; ++j) {
    float aa = 0.f;
    #pragma unroll
    for (int tq = 0; tq < 4; ++tq) {
      float4 a4 = *(const float4*)&anT[j*20 + 4*tq];
      aa += a4.x*x1[4*tq] + a4.y*x1[4*tq+1] + a4.z*x1[4*tq+2] + a4.w*x1[4*tq+3];
    }
    float4 a4 = *(const float4*)&anT[j*20 + 16];
    aa += a4.x*x1[16] + a4.y*x1[17] + a4.z*x1[18];
    hb[j*Dd + lane] += HOPW*aa;
  }
  wsync();

  // ---- matmul1 + residual + LN1 + store ----
  float acc1[Nn];
  #pragma unroll
  for (int n = 0; n < Nn; ++n) acc1[n] = 0.f;
  {
    const float4* w1r = (const float4*)(W1 + lane*Dd);
    #pragma unroll
    for (int tq = 0; tq < Dd/4; ++tq) {
      float4 w4 = w1r[tq];
      #pragma unroll
      for (int n = 0; n < Nn; ++n) {
        float4 h4 = *(const float4*)&hb[n*Dd + 4*tq];
        acc1[n] += h4.x*w4.x + h4.y*w4.y + h4.z*w4.z + h4.w*w4.w;
      }
    }
  }
  {
    float bias = b1[lane], gam = g1[lane], bet = be1[lane];
    float* ob = out + (((size_t)b*Nn)*Tt + t)*Dd + lane;
    #pragma unroll
    for (int n = 0; n < Nn; ++n) {
      float v  = acc1[n] + bias + yv[n];
      float mu = wsum(v)*(1.f/64.f);
      float d  = v - mu;
      float var = wsum(d*d)*(1.f/64.f);
      ob[(size_t)n*Tt*Dd] = d*rsqrtf(var + LNEPS)*gam + bet;
    }
  }
}

// ======================= fallback: round-1 monolithic kernel =======================
__global__ __launch_bounds__(64)
void gcm_mono(
  const float* __restrict__ feat,
  const float* __restrict__ adj,
  const float* __restrict__ ew_p, const float* __restrict__ eb_p,
  const float* __restrict__ W0, const float* __restrict__ b0,
  const float* __restrict__ W1, const float* __restrict__ b1,
  const float* __restrict__ g0, const float* __restrict__ be0,
  const float* __restrict__ g1, const float* __restrict__ be1,
  float* __restrict__ out)
{
  const int g    = blockIdx.x;
  const int lane = threadIdx.x;
  const int b    = g >> 10;
  const int t    = g & (Tt - 1);

  __shared__ float  anS[Nn*Nn];
  __shared__ float  peS[Nn*KE];
  __shared__ double evS[Nn];
  __shared__ float  rsS[Nn];
  __shared__ float  csS[Nn];
  __shared__ __align__(16) char arena[6080];
  double* Ad   = (double*)(arena);
  float*  Vf   = (float*)(arena + 3040);
  float*  adjS = (float*)(arena + 4560);
  float*  hb   = (float*)(arena);

  float xr[Nn];
  const float* fb = feat + (((size_t)b*Nn)*Tt + t)*Dd + lane;
  #pragma unroll
  for (int n = 0; n < Nn; ++n) xr[n] = fb[(size_t)n*Tt*Dd];

  const float ew = ew_p[0], eb = eb_p[0];

  for (int idx = lane; idx < Nn*Nn; idx += 64)
    adjS[idx] = adj[(size_t)g*(Nn*Nn) + idx];
  __syncthreads();

  if (lane < Nn) {
    float rs = 0.f;
    for (int j = 0; j < Nn; ++j) rs += adjS[lane*Nn + j];
    rsS[lane] = rsqrtf(fmaxf(rs, 1e-6f));
  }
  for (int idx = lane; idx < Nn*Nn; idx += 64) {
    int i = idx / Nn, j = idx - i*Nn;
    float a = adjS[idx];
    bool m = a > 0.f;
    float wv = m ? softplusf(a*ew + eb) : ((i == j) ? 1.f : 0.f);
    anS[idx] = wv;
  }
  __syncthreads();
  if (lane < Nn) {
    float cs = 0.f;
    for (int i = 0; i < Nn; ++i) cs += anS[i*Nn + lane];
    csS[lane] = (cs > 0.f) ? rsqrtf(fmaxf(cs, 1e-30f)) : 0.f;
  }
  __syncthreads();
  for (int idx = lane; idx < Nn*Nn; idx += 64) {
    int i = idx / Nn, j = idx - i*Nn;
    anS[idx] = csS[i]*anS[idx]*csS[j];
    float anij = rsS[i]*adjS[i*Nn + j]*rsS[j];
    float anji = rsS[j]*adjS[j*Nn + i]*rsS[i];
    double m = ((i == j) ? (1.0 + 1e-5) : 0.0) - 0.5*((double)anij + (double)anji);
    Ad[i*20 + j] = m;
    Vf[i*20 + j] = (i == j) ? 1.f : 0.f;
  }
  __syncthreads();

  for (int sweep = 0; sweep < 30; ++sweep) {
    double off = 0.0;
    for (int idx = lane; idx < Nn*Nn; idx += 64) {
      int i = idx / Nn, j = idx - i*Nn;
      if (i < j) { double v = Ad[i*20 + j]; off += v*v; }
    }
    #pragma unroll
    for (int o = 32; o > 0; o >>= 1) off += __shfl_xor(off, o, 64);
    if (off < 1e-22) break;
    for (int p = 0; p < Nn - 1; ++p) {
      for (int q = p + 1; q < Nn; ++q) {
        double apq = Ad[p*20 + q];
        if (fabs(apq) > 1e-15) {
          double app = Ad[p*20 + p], aqq = Ad[q*20 + q];
          double tau = (aqq - app) / (2.0*apq);
          double tt  = sqrt(1.0 + tau*tau);
          double tv  = (tau >= 0.0) ? 1.0/(tau + tt) : 1.0/(tau - tt);
          double c   = 1.0/sqrt(1.0 + tv*tv);
          double s   = tv*c;
          double akp = 0.0, akq = 0.0; float vkp = 0.f, vkq = 0.f;
          if (lane < Nn) {
            akp = Ad[lane*20 + p]; akq = Ad[lane*20 + q];
            vkp = Vf[lane*20 + p]; vkq = Vf[lane*20 + q];
          }
          __syncthreads();
          if (lane < Nn) {
            double nkp = c*akp - s*akq;
            double nkq = s*akp + c*akq;
            if (lane == p) {
              nkp = c*c*app - 2.0*c*s*apq + s*s*aqq;
              nkq = 0.0;
            } else if (lane == q) {
              nkp = 0.0;
              nkq = s*s*app + 2.0*c*s*apq + c*c*aqq;
            }
            Ad[lane*20 + p] = nkp; Ad[p*20 + lane] = nkp;
            Ad[lane*20 + q] = nkq; Ad[q*20 + lane] = nkq;
            float fc = (float)c, fs = (float)s;
            Vf[lane*20 + p] = fc*vkp - fs*vkq;
            Vf[lane*20 + q] = fs*vkp + fc*vkq;
          }
          __syncthreads();
        }
      }
    }
  }

  if (lane < Nn) evS[lane] = Ad[lane*20 + lane];
  __syncthreads();
  if (lane < Nn) {
    double lam = evS[lane];
    int r = 0;
    for (int j = 0; j < Nn; ++j) {
      double lj = evS[j];
      r += (lj < lam) || (lj == lam && j < lane);
    }
    if (r < KE) {
      float sacc = 0.f;
      for (int n = 0; n < Nn; ++n) sacc += Vf[n*20 + lane];
      float sgn = (sacc < 0.f) ? -1.f : 1.f;
      for (int n = 0; n < Nn; ++n) peS[n*KE + r] = Vf[n*20 + lane]*sgn;
    }
  }
  __syncthreads();

  {
    float x1[Nn], x2[Nn];
    for (int j = 0; j < Nn; ++j) {
      float a2 = 0.f;
      #pragma unroll
      for (int i = 0; i < Nn; ++i) a2 += anS[i*Nn + j]*xr[i];
      x1[j] = a2;
    }
    for (int j = 0; j < Nn; ++j) {
      float a2 = 0.f;
      #pragma unroll
      for (int i = 0; i < Nn; ++i) a2 += anS[i*Nn + j]*x1[i];
      x2[j] = a2;
    }
    #pragma unroll
    for (int n = 0; n < Nn; ++n)
      hb[n*DIN + lane] = ALPHAc*xr[n] + HOPW*(x1[n] + x2[n]);
  }
  if (lane < KE) {
    float xc[Nn], x1[Nn], x2[Nn];
    #pragma unroll
    for (int n = 0; n < Nn; ++n) xc[n] = peS[n*KE + lane];
    for (int j = 0; j < Nn; ++j) {
      float a2 = 0.f;
      #pragma unroll
      for (int i = 0; i < Nn; ++i) a2 += anS[i*Nn + j]*xc[i];
      x1[j] = a2;
    }
    for (int j = 0; j < Nn; ++j) {
      float a2 = 0.f;
      #pragma unroll
      for (int i = 0; i < Nn; ++i) a2 += anS[i*Nn + j]*x1[i];
      x2[j] = a2;
    }
    #pragma unroll
    for (int n = 0; n < Nn; ++n)
      hb[n*DIN + Dd + lane] = ALPHAc*xc[n] + HOPW*(x1[n] + x2[n]);
  }
  __syncthreads();

  float acc[Nn];
  #pragma unroll
  for (int n = 0; n < Nn; ++n) acc[n] = 0.f;
  {
    const float* w0r = W0 + lane*DIN;
    #pragma unroll 8
    for (int k = 0; k < DIN; ++k) {
      float wv = w0r[k];
      #pragma unroll
      for (int n = 0; n < Nn; ++n) acc[n] += hb[n*DIN + k]*wv;
    }
  }
  float yv[Nn];
  {
    float bias = b0[lane], gam = g0[lane], bet = be0[lane];
    #pragma unroll
    for (int n = 0; n < Nn; ++n) {
      float v  = acc[n] + bias;
      float mu = wsum(v)*(1.f/64.f);
      float d  = v - mu;
      float var = wsum(d*d)*(1.f/64.f);
      yv[n] = d*rsqrtf(var + LNEPS)*gam + bet;
    }
  }

  {
    float x1[Nn], x2[Nn];
    for (int j = 0; j < Nn; ++j) {
      float a2 = 0.f;
      #pragma unroll
      for (int i = 0; i < Nn; ++i) a2 += anS[i*Nn + j]*yv[i];
      x1[j] = a2;
    }
    for (int j = 0; j < Nn; ++j) {
      float a2 = 0.f;
      #pragma unroll
      for (int i = 0; i < Nn; ++i) a2 += anS[i*Nn + j]*x1[i];
      x2[j] = a2;
    }
    __syncthreads();
    #pragma unroll
    for (int n = 0; n < Nn; ++n)
      hb[n*Dd + lane] = ALPHAc*yv[n] + HOPW*(x1[n] + x2[n]);
    __syncthreads();
  }

  float acc1[Nn];
  #pragma unroll
  for (int n = 0; n < Nn; ++n) acc1[n] = 0.f;
  {
    const float* w1r = W1 + lane*Dd;
    #pragma unroll 8
    for (int k = 0; k < Dd; ++k) {
      float wv = w1r[k];
      #pragma unroll
      for (int n = 0; n < Nn; ++n) acc1[n] += hb[n*Dd + k]*wv;
    }
  }
  {
    float bias = b1[lane], gam = g1[lane], bet = be1[lane];
    float* ob = out + (((size_t)b*Nn)*Tt + t)*Dd + lane;
    #pragma unroll
    for (int n = 0; n < Nn; ++n) {
      float v  = acc1[n] + bias + yv[n];
      float mu = wsum(v)*(1.f/64.f);
      float d  = v - mu;
      float var = wsum(d*d)*(1.f/64.f);
      ob[(size_t)n*Tt*Dd] = d*rsqrtf(var + LNEPS)*gam + bet;
    }
  }
}

extern "C" void kernel_launch(void* const* d_in, const int* in_sizes, int n_in,
                              void* d_out, int out_size, void* d_ws, size_t ws_size,
                              hipStream_t stream) {
  (void)in_sizes; (void)n_in; (void)out_size;
  const float* feat = (const float*)d_in[0];
  const float* adj  = (const float*)d_in[1];
  const float* ew   = (const float*)d_in[2];
  const float* eb   = (const float*)d_in[3];
  const float* W0   = (const float*)d_in[4];
  const float* b0   = (const float*)d_in[5];
  const float* W1   = (const float*)d_in[6];
  const float* b1   = (const float*)d_in[7];
  const float* g0   = (const float*)d_in[8];
  const float* be0  = (const float*)d_in[9];
  const float* g1   = (const float*)d_in[10];
  const float* be1  = (const float*)d_in[11];
  float* out = (float*)d_out;

  if (ws_size >= WS_NEED) {
    float* anW = (float*)d_ws;
    float* peW = anW + (size_t)Gg*AN_STRIDE;
    hipLaunchKernelGGL(eig_kernel, dim3(Gg/4), dim3(256), 0, stream,
                       adj, ew, eb, anW, peW);
    hipLaunchKernelGGL(gnn_kernel, dim3(Gg), dim3(64), 0, stream,
                       feat, anW, peW, W0, b0, W1, b1, g0, be0, g1, be1, out);
  } else {
    hipLaunchKernelGGL(gcm_mono, dim3(Gg), dim3(64), 0, stream,
                       feat, adj, ew, eb, W0, b0, W1, b1, g0, be0, g1, be1, out);
  }
}

// Round 3
// 1102.728 us; speedup vs baseline: 7.4336x; 1.4593x over previous
//
#include <hip/hip_runtime.h>
#include <math.h>

#define Nn 19
#define Dd 64
#define KE 16
#define DIN 80
#define Tt 1024
#define Bb 16
#define Gg (Bb*Tt)
#define ALPHAc 0.05f
#define HOPW 0.475f
#define LNEPS 1e-5f

#define AN_STRIDE 384            // floats per graph: transposed a_norm rows of 20
#define PE_STRIDE 304
#define WS_NEED ((size_t)Gg * (AN_STRIDE + PE_STRIDE) * 4)

__device__ __forceinline__ float softplusf(float x){
  return (x > 0.f) ? (x + log1pf(expf(-x))) : log1pf(expf(x));
}

__device__ __forceinline__ float wsum(float v){
  #pragma unroll
  for (int o = 32; o > 0; o >>= 1) v += __shfl_xor(v, o, 64);
  return v;
}

__device__ __forceinline__ float rlanef(float v, int l){
  return __int_as_float(__builtin_amdgcn_readlane(__float_as_int(v), l));
}

// intra-wave LDS ordering fence (compile barrier + wave_barrier, 0 instructions)
__device__ __forceinline__ void wsync(){
  __asm__ volatile("" ::: "memory");
  __builtin_amdgcn_wave_barrier();
  __asm__ volatile("" ::: "memory");
}

// ======================= kernel 1: gcn_norm + eigensolver =======================
// 4 waves/block, one graph per wave, per-wave LDS arena, no block barriers.
// Ad: 19x21 fp64 (stride 21 -> bank-conflict-free), Vf: 19x21 fp32.
#define ARENA_BYTES 6528
__global__ __launch_bounds__(256)
void eig_kernel(const float* __restrict__ adj,
                const float* __restrict__ ew_p, const float* __restrict__ eb_p,
                float* __restrict__ anW, float* __restrict__ peW)
{
  const int wid  = threadIdx.x >> 6;
  const int lane = threadIdx.x & 63;
  const int g    = blockIdx.x * 4 + wid;

  __shared__ __align__(16) char arenaAll[4 * ARENA_BYTES];
  char* arena = arenaAll + wid * ARENA_BYTES;
  double* Ad  = (double*)(arena);            // [19][21] fp64 (3192 B)
  float*  Vf  = (float*) (arena + 3200);     // [19][21] fp32 (1596 B)
  float*  adjS= (float*) (arena + 3200);     // [361] raw adj (overlaps Vf; dead before Vf init)
  float*  peB = (float*) (arena + 4800);     // [304] pe staging
  float*  wS  = (float*) (arena + 4800);     // [361] softplus weights (dead before peB use)
  float*  rsS = (float*) (arena + 6256);     // [19]
  float*  csS = (float*) (arena + 6336);     // [19]
  float*  cS  = (float*) (arena + 6416);     // [9]
  float*  sS  = (float*) (arena + 6456);     // [9]

  const float ew = ew_p[0], eb = eb_p[0];

  for (int idx = lane; idx < Nn*Nn; idx += 64)
    adjS[idx] = adj[(size_t)g*(Nn*Nn) + idx];
  wsync();

  for (int idx = lane; idx < Nn*Nn; idx += 64) {
    int i = idx / Nn, j = idx - i*Nn;
    float a = adjS[idx];
    wS[idx] = (a > 0.f) ? softplusf(a*ew + eb) : ((i == j) ? 1.f : 0.f);
  }
  if (lane < Nn) {
    float rs = 0.f;
    for (int j = 0; j < Nn; ++j) rs += adjS[lane*Nn + j];
    rsS[lane] = rsqrtf(fmaxf(rs, 1e-6f));
  }
  wsync();
  if (lane < Nn) {
    float cs = 0.f;
    for (int i = 0; i < Nn; ++i) cs += wS[i*Nn + lane];
    csS[lane] = (cs > 0.f) ? rsqrtf(fmaxf(cs, 1e-30f)) : 0.f;
  }
  wsync();
  // write TRANSPOSED normalized adjacency to ws: anW[g][j*20+i] = an[i][j]
  for (int idx = lane; idx < Nn*Nn; idx += 64) {
    int i = idx / Nn, j = idx - i*Nn;
    anW[(size_t)g*AN_STRIDE + j*20 + i] = csS[i]*wS[idx]*csS[j];
  }
  // symmetrized Laplacian (fp64), stride 21; pads zeroed
  for (int idx = lane; idx < Nn*Nn; idx += 64) {
    int i = idx / Nn, j = idx - i*Nn;
    float anij = rsS[i]*adjS[i*Nn + j]*rsS[j];
    float anji = rsS[j]*adjS[j*Nn + i]*rsS[i];
    Ad[i*21 + j] = ((i == j) ? (1.0 + 1e-5) : 0.0) - 0.5*((double)anij + (double)anji);
  }
  if (lane < Nn) { Ad[lane*21 + 19] = 0.0; Ad[lane*21 + 20] = 0.0; }
  wsync();
  for (int idx = lane; idx < Nn*21; idx += 64) {
    int i = idx / 21;
    Vf[idx] = (idx == i*22) ? 1.f : 0.f;
  }
  wsync();

  // per-lane pair state (round-robin with bye). items: (k,i), k<19, i in 1..9
  int aR[3], bR[3], kR[3], k21R[3], iR0[3];
  #pragma unroll
  for (int it = 0; it < 3; ++it) {
    int item = lane + it*64;
    int k = item / 9, i0 = item - k*9;          // i0 in 0..8 -> pair i0+1
    kR[it] = k; k21R[it] = k*21; iR0[it] = i0;
    aR[it] = i0 + 1;                            // (r=0 + i)
    bR[it] = 18 - i0;                           // (r=0 + 19 - i) mod 19
  }
  int aA = lane + 1, bA = 18 - lane;            // angle lanes (lane<9 -> pair i=lane+1)

  for (int sweep = 0; sweep < 14; ++sweep) {
    if (sweep) {
      double off = 0.0;
      for (int idx = lane; idx < Nn*21; idx += 64) { double v = Ad[idx]; off += v*v; }
      if (lane < Nn) { double d = Ad[lane*22]; off -= d*d; }
      #pragma unroll
      for (int o = 32; o > 0; o >>= 1) off += __shfl_xor(off, o, 64);
      if (off < 1e-10) break;
    }

    for (int r = 0; r < Nn; ++r) {
      bool active = false;
      if (lane < 9) {
        int p = min(aA, bA), q = max(aA, bA);
        float apq = (float)Ad[p*21 + q];
        float c = 1.f, s = 0.f;
        if (fabsf(apq) > 1e-12f) {
          float app = (float)Ad[p*22], aqq = (float)Ad[q*22];
          float tau = (aqq - app) / (2.f*apq);
          float tt  = sqrtf(1.f + tau*tau);
          float tv  = (tau >= 0.f) ? 1.f/(tau + tt) : 1.f/(tau - tt);
          c = rsqrtf(1.f + tv*tv);
          s = tv*c;
          active = true;
        }
        cS[lane] = c; sS[lane] = s;
      }
      int anyact = __any(active);
      wsync();

      if (anyact) {
        float cI[3], sI[3]; int pI[3], qI[3];
        #pragma unroll
        for (int it = 0; it < 3; ++it) {
          cI[it] = cS[iR0[it]]; sI[it] = sS[iR0[it]];
          pI[it] = min(aR[it], bR[it]); qI[it] = max(aR[it], bR[it]);
        }
        // phase A: A <- A*J (columns), V <- V*J
        #pragma unroll
        for (int it = 0; it < 3; ++it) {
          if (lane + it*64 < 171) {
            int p = pI[it], q = qI[it], base = k21R[it];
            double cd = (double)cI[it], sd = (double)sI[it];
            double akp = Ad[base + p], akq = Ad[base + q];
            Ad[base + p] = cd*akp - sd*akq;
            Ad[base + q] = sd*akp + cd*akq;
            float vkp = Vf[base + p], vkq = Vf[base + q];
            Vf[base + p] = cI[it]*vkp - sI[it]*vkq;
            Vf[base + q] = sI[it]*vkp + cI[it]*vkq;
          }
        }
        wsync();
        // phase B: A <- J^T*A (rows)
        #pragma unroll
        for (int it = 0; it < 3; ++it) {
          if (lane + it*64 < 171) {
            int p21 = pI[it]*21, q21 = qI[it]*21, k = kR[it];
            double cd = (double)cI[it], sd = (double)sI[it];
            double arp = Ad[p21 + k], arq = Ad[q21 + k];
            Ad[p21 + k] = cd*arp - sd*arq;
            Ad[q21 + k] = sd*arp + cd*arq;
          }
        }
        wsync();
      }

      // increment pair state: a,b += 1 (mod 19)
      #pragma unroll
      for (int it = 0; it < 3; ++it) {
        int t1 = aR[it] + 1; aR[it] = (t1 >= 19) ? t1 - 19 : t1;
        int t2 = bR[it] + 1; bR[it] = (t2 >= 19) ? t2 - 19 : t2;
      }
      { int t1 = aA + 1; aA = (t1 >= 19) ? t1 - 19 : t1;
        int t2 = bA + 1; bA = (t2 >= 19) ? t2 - 19 : t2; }
    }
  }

  // rank eigenvalues, sign-fix, stage pe, write out
  if (lane < Nn) {
    double lam = Ad[lane*22];
    int rk = 0;
    for (int j = 0; j < Nn; ++j) {
      double lj = Ad[j*22];
      rk += (lj < lam) || (lj == lam && j < lane);
    }
    if (rk < KE) {
      float sacc = 0.f;
      for (int n = 0; n < Nn; ++n) sacc += Vf[n*21 + lane];
      float sgn = (sacc < 0.f) ? -1.f : 1.f;
      for (int n = 0; n < Nn; ++n) peB[n*KE + rk] = Vf[n*21 + lane]*sgn;
    }
  }
  wsync();
  for (int idx = lane; idx < Nn*KE; idx += 64)
    peW[(size_t)g*PE_STRIDE + idx] = peB[idx];
}

// ======================= kernel 2: SSGConv x2 + LN (LDS-free) =======================
__global__ __launch_bounds__(64)
void gnn_kernel(const float* __restrict__ feat,
                const float* __restrict__ anW, const float* __restrict__ peW,
                const float* __restrict__ W0, const float* __restrict__ b0,
                const float* __restrict__ W1, const float* __restrict__ b1,
                const float* __restrict__ g0, const float* __restrict__ be0,
                const float* __restrict__ g1, const float* __restrict__ be1,
                float* __restrict__ out)
{
  const int g = blockIdx.x, lane = threadIdx.x;
  const int b = g >> 10, t = g & (Tt - 1);

  const float* an = anW + (size_t)g*AN_STRIDE;   // wave-uniform rows (transposed a_norm)

  float xa[Nn], xb[Nn];
  const float* fb = feat + (((size_t)b*Nn)*Tt + t)*Dd + lane;
  #pragma unroll
  for (int n = 0; n < Nn; ++n) xa[n] = fb[(size_t)n*Tt*Dd];
  #pragma unroll
  for (int n = 0; n < Nn; ++n)
    xb[n] = (lane < KE) ? peW[(size_t)g*PE_STRIDE + n*KE + lane] : 0.f;

  // ---- layer0 hop1 ----
  float x1a[Nn], x1b[Nn];
  for (int j = 0; j < Nn; ++j) {
    float aa = 0.f, ab = 0.f;
    #pragma unroll
    for (int i = 0; i < Nn; ++i) {
      float av = an[j*20 + i];
      aa = fmaf(av, xa[i], aa);
      ab = fmaf(av, xb[i], ab);
    }
    x1a[j] = aa; x1b[j] = ab;
  }
  float h0a[Nn], h0b[Nn];
  #pragma unroll
  for (int n = 0; n < Nn; ++n) {
    h0a[n] = ALPHAc*xa[n] + HOPW*x1a[n];
    h0b[n] = ALPHAc*xb[n] + HOPW*x1b[n];
  }
  // ---- layer0 hop2 ----
  for (int j = 0; j < Nn; ++j) {
    float aa = 0.f, ab = 0.f;
    #pragma unroll
    for (int i = 0; i < Nn; ++i) {
      float av = an[j*20 + i];
      aa = fmaf(av, x1a[i], aa);
      ab = fmaf(av, x1b[i], ab);
    }
    h0a[j] += HOPW*aa;
    h0b[j] += HOPW*ab;
  }

  // ---- matmul0 (readlane broadcast of h columns) + LN0 ----
  float acc[Nn];
  #pragma unroll
  for (int n = 0; n < Nn; ++n) acc[n] = 0.f;
  {
    const float* w0p = W0 + lane*DIN;
    #pragma unroll
    for (int kb = 0; kb < 64; kb += 16) {
      float w[16];
      #pragma unroll
      for (int q4 = 0; q4 < 4; ++q4)
        *(float4*)&w[4*q4] = *(const float4*)(w0p + kb + 4*q4);
      #pragma unroll
      for (int kk = 0; kk < 16; ++kk) {
        int k = kb + kk;
        #pragma unroll
        for (int n = 0; n < Nn; ++n)
          acc[n] = fmaf(rlanef(h0a[n], k), w[kk], acc[n]);
      }
    }
    float w[16];
    #pragma unroll
    for (int q4 = 0; q4 < 4; ++q4)
      *(float4*)&w[4*q4] = *(const float4*)(w0p + 64 + 4*q4);
    #pragma unroll
    for (int kk = 0; kk < 16; ++kk) {
      #pragma unroll
      for (int n = 0; n < Nn; ++n)
        acc[n] = fmaf(rlanef(h0b[n], kk), w[kk], acc[n]);
    }
  }
  float yv[Nn];
  {
    float bias = b0[lane], gam = g0[lane], bet = be0[lane];
    #pragma unroll
    for (int n = 0; n < Nn; ++n) {
      float v  = acc[n] + bias;
      float mu = wsum(v)*(1.f/64.f);
      float d  = v - mu;
      float var = wsum(d*d)*(1.f/64.f);
      yv[n] = d*rsqrtf(var + LNEPS)*gam + bet;
    }
  }

  // ---- layer1 hops ----
  float x1c[Nn];
  for (int j = 0; j < Nn; ++j) {
    float aa = 0.f;
    #pragma unroll
    for (int i = 0; i < Nn; ++i)
      aa = fmaf(an[j*20 + i], yv[i], aa);
    x1c[j] = aa;
  }
  float h1[Nn];
  #pragma unroll
  for (int n = 0; n < Nn; ++n) h1[n] = ALPHAc*yv[n] + HOPW*x1c[n];
  for (int j = 0; j < Nn; ++j) {
    float aa = 0.f;
    #pragma unroll
    for (int i = 0; i < Nn; ++i)
      aa = fmaf(an[j*20 + i], x1c[i], aa);
    h1[j] += HOPW*aa;
  }

  // ---- matmul1 + residual + LN1 + store ----
  float acc1[Nn];
  #pragma unroll
  for (int n = 0; n < Nn; ++n) acc1[n] = 0.f;
  {
    const float* w1p = W1 + lane*Dd;
    #pragma unroll
    for (int kb = 0; kb < 64; kb += 16) {
      float w[16];
      #pragma unroll
      for (int q4 = 0; q4 < 4; ++q4)
        *(float4*)&w[4*q4] = *(const float4*)(w1p + kb + 4*q4);
      #pragma unroll
      for (int kk = 0; kk < 16; ++kk) {
        int k = kb + kk;
        #pragma unroll
        for (int n = 0; n < Nn; ++n)
          acc1[n] = fmaf(rlanef(h1[n], k), w[kk], acc1[n]);
      }
    }
  }
  {
    float bias = b1[lane], gam = g1[lane], bet = be1[lane];
    float* ob = out + (((size_t)b*Nn)*Tt + t)*Dd + lane;
    #pragma unroll
    for (int n = 0; n < Nn; ++n) {
      float v  = acc1[n] + bias + yv[n];
      float mu = wsum(v)*(1.f/64.f);
      float d  = v - mu;
      float var = wsum(d*d)*(1.f/64.f);
      ob[(size_t)n*Tt*Dd] = d*rsqrtf(var + LNEPS)*gam + bet;
    }
  }
}

// ======================= fallback: monolithic kernel (round-1, known-correct) =======================
__global__ __launch_bounds__(64)
void gcm_mono(
  const float* __restrict__ feat,
  const float* __restrict__ adj,
  const float* __restrict__ ew_p, const float* __restrict__ eb_p,
  const float* __restrict__ W0, const float* __restrict__ b0,
  const float* __restrict__ W1, const float* __restrict__ b1,
  const float* __restrict__ g0, const float* __restrict__ be0,
  const float* __restrict__ g1, const float* __restrict__ be1,
  float* __restrict__ out)
{
  const int g    = blockIdx.x;
  const int lane = threadIdx.x;
  const int b    = g >> 10;
  const int t    = g & (Tt - 1);

  __shared__ float  anS[Nn*Nn];
  __shared__ float  peS[Nn*KE];
  __shared__ double evS[Nn];
  __shared__ float  rsS[Nn];
  __shared__ float  csS[Nn];
  __shared__ __align__(16) char arena[6080];
  double* Ad   = (double*)(arena);
  float*  Vf   = (float*)(arena + 3040);
  float*  adjS = (float*)(arena + 4560);
  float*  hb   = (float*)(arena);

  float xr[Nn];
  const float* fb = feat + (((size_t)b*Nn)*Tt + t)*Dd + lane;
  #pragma unroll
  for (int n = 0; n < Nn; ++n) xr[n] = fb[(size_t)n*Tt*Dd];

  const float ew = ew_p[0], eb = eb_p[0];

  for (int idx = lane; idx < Nn*Nn; idx += 64)
    adjS[idx] = adj[(size_t)g*(Nn*Nn) + idx];
  __syncthreads();

  if (lane < Nn) {
    float rs = 0.f;
    for (int j = 0; j < Nn; ++j) rs += adjS[lane*Nn + j];
    rsS[lane] = rsqrtf(fmaxf(rs, 1e-6f));
  }
  for (int idx = lane; idx < Nn*Nn; idx += 64) {
    int i = idx / Nn, j = idx - i*Nn;
    float a = adjS[idx];
    bool m = a > 0.f;
    float wv = m ? softplusf(a*ew + eb) : ((i == j) ? 1.f : 0.f);
    anS[idx] = wv;
  }
  __syncthreads();
  if (lane < Nn) {
    float cs = 0.f;
    for (int i = 0; i < Nn; ++i) cs += anS[i*Nn + lane];
    csS[lane] = (cs > 0.f) ? rsqrtf(fmaxf(cs, 1e-30f)) : 0.f;
  }
  __syncthreads();
  for (int idx = lane; idx < Nn*Nn; idx += 64) {
    int i = idx / Nn, j = idx - i*Nn;
    anS[idx] = csS[i]*anS[idx]*csS[j];
    float anij = rsS[i]*adjS[i*Nn + j]*rsS[j];
    float anji = rsS[j]*adjS[j*Nn + i]*rsS[i];
    double m = ((i == j) ? (1.0 + 1e-5) : 0.0) - 0.5*((double)anij + (double)anji);
    Ad[i*20 + j] = m;
    Vf[i*20 + j] = (i == j) ? 1.f : 0.f;
  }
  __syncthreads();

  for (int sweep = 0; sweep < 30; ++sweep) {
    double off = 0.0;
    for (int idx = lane; idx < Nn*Nn; idx += 64) {
      int i = idx / Nn, j = idx - i*Nn;
      if (i < j) { double v = Ad[i*20 + j]; off += v*v; }
    }
    #pragma unroll
    for (int o = 32; o > 0; o >>= 1) off += __shfl_xor(off, o, 64);
    if (off < 1e-22) break;
    for (int p = 0; p < Nn - 1; ++p) {
      for (int q = p + 1; q < Nn; ++q) {
        double apq = Ad[p*20 + q];
        if (fabs(apq) > 1e-15) {
          double app = Ad[p*20 + p], aqq = Ad[q*20 + q];
          double tau = (aqq - app) / (2.0*apq);
          double tt  = sqrt(1.0 + tau*tau);
          double tv  = (tau >= 0.0) ? 1.0/(tau + tt) : 1.0/(tau - tt);
          double c   = 1.0/sqrt(1.0 + tv*tv);
          double s   = tv*c;
          double akp = 0.0, akq = 0.0; float vkp = 0.f, vkq = 0.f;
          if (lane < Nn) {
            akp = Ad[lane*20 + p]; akq = Ad[lane*20 + q];
            vkp = Vf[lane*20 + p]; vkq = Vf[lane*20 + q];
          }
          __syncthreads();
          if (lane < Nn) {
            double nkp = c*akp - s*akq;
            double nkq = s*akp + c*akq;
            if (lane == p) {
              nkp = c*c*app - 2.0*c*s*apq + s*s*aqq;
              nkq = 0.0;
            } else if (lane == q) {
              nkp = 0.0;
              nkq = s*s*app + 2.0*c*s*apq + c*c*aqq;
            }
            Ad[lane*20 + p] = nkp; Ad[p*20 + lane] = nkp;
            Ad[lane*20 + q] = nkq; Ad[q*20 + lane] = nkq;
            float fc = (float)c, fs = (float)s;
            Vf[lane*20 + p] = fc*vkp - fs*vkq;
            Vf[lane*20 + q] = fs*vkp + fc*vkq;
          }
          __syncthreads();
        }
      }
    }
  }

  if (lane < Nn) evS[lane] = Ad[lane*20 + lane];
  __syncthreads();
  if (lane < Nn) {
    double lam = evS[lane];
    int r = 0;
    for (int j = 0; j < Nn; ++j) {
      double lj = evS[j];
      r += (lj < lam) || (lj == lam && j < lane);
    }
    if (r < KE) {
      float sacc = 0.f;
      for (int n = 0; n < Nn; ++n) sacc += Vf[n*20 + lane];
      float sgn = (sacc < 0.f) ? -1.f : 1.f;
      for (int n = 0; n < Nn; ++n) peS[n*KE + r] = Vf[n*20 + lane]*sgn;
    }
  }
  __syncthreads();

  {
    float x1[Nn], x2[Nn];
    for (int j = 0; j < Nn; ++j) {
      float a2 = 0.f;
      #pragma unroll
      for (int i = 0; i < Nn; ++i) a2 += anS[i*Nn + j]*xr[i];
      x1[j] = a2;
    }
    for (int j = 0; j < Nn; ++j) {
      float a2 = 0.f;
      #pragma unroll
      for (int i = 0; i < Nn; ++i) a2 += anS[i*Nn + j]*x1[i];
      x2[j] = a2;
    }
    #pragma unroll
    for (int n = 0; n < Nn; ++n)
      hb[n*DIN + lane] = ALPHAc*xr[n] + HOPW*(x1[n] + x2[n]);
  }
  if (lane < KE) {
    float xc[Nn], x1[Nn], x2[Nn];
    #pragma unroll
    for (int n = 0; n < Nn; ++n) xc[n] = peS[n*KE + lane];
    for (int j = 0; j < Nn; ++j) {
      float a2 = 0.f;
      #pragma unroll
      for (int i = 0; i < Nn; ++i) a2 += anS[i*Nn + j]*xc[i];
      x1[j] = a2;
    }
    for (int j = 0; j < Nn; ++j) {
      float a2 = 0.f;
      #pragma unroll
      for (int i = 0; i < Nn; ++i) a2 += anS[i*Nn + j]*x1[i];
      x2[j] = a2;
    }
    #pragma unroll
    for (int n = 0; n < Nn; ++n)
      hb[n*DIN + Dd + lane] = ALPHAc*xc[n] + HOPW*(x1[n] + x2[n]);
  }
  __syncthreads();

  float acc[Nn];
  #pragma unroll
  for (int n = 0; n < Nn; ++n) acc[n] = 0.f;
  {
    const float* w0r = W0 + lane*DIN;
    #pragma unroll 8
    for (int k = 0; k < DIN; ++k) {
      float wv = w0r[k];
      #pragma unroll
      for (int n = 0; n < Nn; ++n) acc[n] += hb[n*DIN + k]*wv;
    }
  }
  float yv[Nn];
  {
    float bias = b0[lane], gam = g0[lane], bet = be0[lane];
    #pragma unroll
    for (int n = 0; n < Nn; ++n) {
      float v  = acc[n] + bias;
      float mu = wsum(v)*(1.f/64.f);
      float d  = v - mu;
      float var = wsum(d*d)*(1.f/64.f);
      yv[n] = d*rsqrtf(var + LNEPS)*gam + bet;
    }
  }

  {
    float x1[Nn], x2[Nn];
    for (int j = 0; j < Nn; ++j) {
      float a2 = 0.f;
      #pragma unroll
      for (int i = 0; i < Nn; ++i) a2 += anS[i*Nn + j]*yv[i];
      x1[j] = a2;
    }
    for (int j = 0; j < Nn; ++j) {
      float a2 = 0.f;
      #pragma unroll
      for (int i = 0; i < Nn; ++i) a2 += anS[i*Nn + j]*x1[i];
      x2[j] = a2;
    }
    __syncthreads();
    #pragma unroll
    for (int n = 0; n < Nn; ++n)
      hb[n*Dd + lane] = ALPHAc*yv[n] + HOPW*(x1[n] + x2[n]);
    __syncthreads();
  }

  float acc1[Nn];
  #pragma unroll
  for (int n = 0; n < Nn; ++n) acc1[n] = 0.f;
  {
    const float* w1r = W1 + lane*Dd;
    #pragma unroll 8
    for (int k = 0; k < Dd; ++k) {
      float wv = w1r[k];
      #pragma unroll
      for (int n = 0; n < Nn; ++n) acc1[n] += hb[n*Dd + k]*wv;
    }
  }
  {
    float bias = b1[lane], gam = g1[lane], bet = be1[lane];
    float* ob = out + (((size_t)b*Nn)*Tt + t)*Dd + lane;
    #pragma unroll
    for (int n = 0; n < Nn; ++n) {
      float v  = acc1[n] + bias + yv[n];
      float mu = wsum(v)*(1.f/64.f);
      float d  = v - mu;
      float var = wsum(d*d)*(1.f/64.f);
      ob[(size_t)n*Tt*Dd] = d*rsqrtf(var + LNEPS)*gam + bet;
    }
  }
}

extern "C" void kernel_launch(void* const* d_in, const int* in_sizes, int n_in,
                              void* d_out, int out_size, void* d_ws, size_t ws_size,
                              hipStream_t stream) {
  (void)in_sizes; (void)n_in; (void)out_size;
  const float* feat = (const float*)d_in[0];
  const float* adj  = (const float*)d_in[1];
  const float* ew   = (const float*)d_in[2];
  const float* eb   = (const float*)d_in[3];
  const float* W0   = (const float*)d_in[4];
  const float* b0   = (const float*)d_in[5];
  const float* W1   = (const float*)d_in[6];
  const float* b1   = (const float*)d_in[7];
  const float* g0   = (const float*)d_in[8];
  const float* be0  = (const float*)d_in[9];
  const float* g1   = (const float*)d_in[10];
  const float* be1  = (const float*)d_in[11];
  float* out = (float*)d_out;

  if (ws_size >= WS_NEED) {
    float* anW = (float*)d_ws;
    float* peW = anW + (size_t)Gg*AN_STRIDE;
    hipLaunchKernelGGL(eig_kernel, dim3(Gg/4), dim3(256), 0, stream,
                       adj, ew, eb, anW, peW);
    hipLaunchKernelGGL(gnn_kernel, dim3(Gg), dim3(64), 0, stream,
                       feat, anW, peW, W0, b0, W1, b1, g0, be0, g1, be1, out);
  } else {
    hipLaunchKernelGGL(gcm_mono, dim3(Gg), dim3(64), 0, stream,
                       feat, adj, ew, eb, W0, b0, W1, b1, g0, be0, g1, be1, out);
  }
}